// Round 2
// baseline (4681.899 us; speedup 1.0000x reference)
//
#include <hip/hip_runtime.h>
#include <stdint.h>
#include <stddef.h>

// BasicNCAModel: 4 NCA steps on x[8,256,256,48], ALL I/O fp32 (per reference).
// Per step: p = [x, dwconv(x,f0), dwconv(x,f1)] (reflect pad), h = leaky(p@w1^T+b1),
// d = h@w2^T, d *= fire(threefry) ; d[:, :3] = 0 ; x += d.

#define B_   8
#define H_   256
#define W_   256
#define C_   48
#define F_   144   // 3*C
#define HID_ 256
#define PW_  64    // pixels per block
#define NTOT (B_*H_*W_*C_)   // 25165824
#define HSTR 260   // padded hidden LDS stride (ushort)

// Fire-mask RNG variant: 0 = partitionable xor (modern JAX default),
// 1 = partitionable word1, 2 = partitionable word0, 3 = legacy non-partitionable.
#define FIRE_MODE 0

struct U2 { unsigned x, y; };

__host__ __device__ __forceinline__ unsigned rotl32(unsigned v, int r) {
  return (v << r) | (v >> (32 - r));
}

// JAX Threefry-2x32, 20 rounds.
__host__ __device__ __forceinline__ U2 threefry2x32(unsigned k0, unsigned k1,
                                                    unsigned x0, unsigned x1) {
  const unsigned k2 = k0 ^ k1 ^ 0x1BD11BDAu;
  x0 += k0; x1 += k1;
#define TF_R(r) { x0 += x1; x1 = rotl32(x1, r); x1 ^= x0; }
  TF_R(13) TF_R(15) TF_R(26) TF_R(6)
  x0 += k1; x1 += k2 + 1u;
  TF_R(17) TF_R(29) TF_R(16) TF_R(24)
  x0 += k2; x1 += k0 + 2u;
  TF_R(13) TF_R(15) TF_R(26) TF_R(6)
  x0 += k0; x1 += k1 + 3u;
  TF_R(17) TF_R(29) TF_R(16) TF_R(24)
  x0 += k1; x1 += k2 + 4u;
  TF_R(13) TF_R(15) TF_R(26) TF_R(6)
  x0 += k2; x1 += k0 + 5u;
#undef TF_R
  U2 r; r.x = x0; r.y = x1; return r;
}

__device__ __forceinline__ float fire_val(unsigned ka, unsigned kb, unsigned j) {
  unsigned bits;
#if FIRE_MODE == 3
  const unsigned HALF = 262144u;  // 524288/2 pixels
  if (j < HALF) { U2 r = threefry2x32(ka, kb, j, j + HALF); bits = r.x; }
  else          { U2 r = threefry2x32(ka, kb, j - HALF, j); bits = r.y; }
#else
  U2 r = threefry2x32(ka, kb, 0u, j);
#if FIRE_MODE == 0
  bits = r.x ^ r.y;
#elif FIRE_MODE == 1
  bits = r.y;
#else
  bits = r.x;
#endif
#endif
  // uniform = bitcast(0x3f800000 | bits>>9) - 1 ; fire iff uniform > 0.5
  return ((bits >> 9) > 4194304u) ? 1.0f : 0.0f;
}

__device__ __forceinline__ float bf2f(unsigned short u) {
  return __uint_as_float(((unsigned)u) << 16);
}
__device__ __forceinline__ unsigned short f2bf(float f) {  // RNE, finite inputs
  unsigned u = __float_as_uint(f);
  unsigned r = u + 0x7FFFu + ((u >> 16) & 1u);
  return (unsigned short)(r >> 16);
}

// One-time per launch: repack weights for coalesced access.
// w1p[(f>>2)*1024 + o*4 + (f&3)]  (float4 per (o, f-chunk), lanes-by-o contiguous)
// w2cm[o*48 + c]
__global__ void nca_pack(const float* __restrict__ w1,
                         const float* __restrict__ w2,
                         float* __restrict__ w1p, float* __restrict__ w2cm) {
  int i = blockIdx.x * 256 + threadIdx.x;
  if (i < HID_ * F_) {
    int o = i / F_, f = i - o * F_;
    w1p[(f >> 2) * (HID_ * 4) + o * 4 + (f & 3)] = w1[i];
  }
  if (i < C_ * HID_) {
    int c = i >> 8, o = i & 255;   // w2 is [C=48][HID=256]
    w2cm[o * C_ + c] = w2[i];
  }
}

__global__ __launch_bounds__(256, 2)
void nca_step(const float* __restrict__ xin, float* __restrict__ xout,
              const float* __restrict__ f0,
              const float* __restrict__ f1,
              const float* __restrict__ w1p,
              const float* __restrict__ b1,
              const float* __restrict__ w2cm,
              unsigned ka, unsigned kb) {
  __shared__ float pL[PW_ * F_];            // 36864 B
  __shared__ unsigned short hS[PW_ * HSTR]; // 33280 B (bf16 bits)
  __shared__ float fireL[PW_];

  const int t = threadIdx.x;
  const int bid = blockIdx.x;
  const int wseg = bid & 3;
  const int h = (bid >> 2) & 255;
  const int b = bid >> 10;
  const int w0 = wseg * PW_;

  if (t < PW_) {
    unsigned j = (unsigned)((b * H_ + h) * W_ + w0 + t);
    fireL[t] = fire_val(ka, kb, j);
  }

  // ---- Phase A: p[pw][0:144] = [x, conv0, conv1] (reflect padding) ----
  const int hr0 = (h == 0) ? 1 : h - 1;
  const int hr2 = (h == 255) ? 254 : h + 1;
  const int hrow[3] = { (b * H_ + hr0) * W_, (b * H_ + h) * W_, (b * H_ + hr2) * W_ };
#pragma unroll
  for (int it = 0; it < 12; ++it) {
    int k = t + it * 256;              // 0..3071 = 64 px * 48 ch
    int pw = k / 48, c = k - pw * 48;
    int w = w0 + pw;
    int wr[3] = { (w == 0) ? 1 : w - 1, w, (w == 255) ? 254 : w + 1 };
    float a0 = 0.f, a1 = 0.f, ctr = 0.f;
#pragma unroll
    for (int iy = 0; iy < 3; ++iy) {
#pragma unroll
      for (int ix = 0; ix < 3; ++ix) {
        float v = xin[(hrow[iy] + wr[ix]) * C_ + c];
        a0 = fmaf(v, f0[c * 9 + iy * 3 + ix], a0);
        a1 = fmaf(v, f1[c * 9 + iy * 3 + ix], a1);
        if (iy == 1 && ix == 1) ctr = v;
      }
    }
    pL[pw * F_ + c]      = ctr;
    pL[pw * F_ + 48 + c] = a0;
    pL[pw * F_ + 96 + c] = a1;
  }
  __syncthreads();

  // ---- Phase B: h = leaky(p @ w1^T + b1); tile = 4 o (stride 64) x 16 pw ----
  {
    const int og = t & 63;      // lane -> o (coalesced w1p float4 reads)
    const int pg = t >> 6;      // wave -> pw quarter (LDS reads broadcast in-wave)
    const int pwb = pg * 16;
    float acc[4][16];
#pragma unroll
    for (int ko = 0; ko < 4; ++ko)
#pragma unroll
      for (int i = 0; i < 16; ++i) acc[ko][i] = 0.f;

    for (int f4 = 0; f4 < F_; f4 += 4) {
      float4 wv[4];
#pragma unroll
      for (int ko = 0; ko < 4; ++ko)
        wv[ko] = *(const float4*)&w1p[(f4 >> 2) * (HID_ * 4) + (og + ko * 64) * 4];
#pragma unroll
      for (int i = 0; i < 16; ++i) {
        const float4 pv = *(const float4*)&pL[(pwb + i) * F_ + f4];
#pragma unroll
        for (int ko = 0; ko < 4; ++ko) {
          float a = acc[ko][i];
          a = fmaf(pv.x, wv[ko].x, a);
          a = fmaf(pv.y, wv[ko].y, a);
          a = fmaf(pv.z, wv[ko].z, a);
          a = fmaf(pv.w, wv[ko].w, a);
          acc[ko][i] = a;
        }
      }
    }
#pragma unroll
    for (int ko = 0; ko < 4; ++ko) {
      const int o = og + ko * 64;
      const float bias = b1[o];
#pragma unroll
      for (int i = 0; i < 16; ++i) {
        float z = acc[ko][i] + bias;
        z = (z >= 0.f) ? z : 0.01f * z;
        hS[(pwb + i) * HSTR + o] = f2bf(z);
      }
    }
  }
  __syncthreads();

  // ---- Phase D: d = h @ w2^T ; fire & channel mask ; x_out = x_in + d ----
  {
    const int pw = t >> 2;         // 64 pixels
    const int c0 = (t & 3) * 12;   // 12 channels per thread
    const unsigned short* hrowp = &hS[pw * HSTR];
    float acc[12];
#pragma unroll
    for (int j = 0; j < 12; ++j) acc[j] = 0.f;

    for (int o = 0; o < HID_; o += 4) {
      ushort4 hv = *(const ushort4*)(hrowp + o);
      float hf[4] = { bf2f(hv.x), bf2f(hv.y), bf2f(hv.z), bf2f(hv.w) };
#pragma unroll
      for (int r = 0; r < 4; ++r) {
#pragma unroll
        for (int s = 0; s < 3; ++s) {
          const float4 q = *(const float4*)&w2cm[(o + r) * C_ + c0 + s * 4];
          acc[s * 4 + 0] = fmaf(hf[r], q.x, acc[s * 4 + 0]);
          acc[s * 4 + 1] = fmaf(hf[r], q.y, acc[s * 4 + 1]);
          acc[s * 4 + 2] = fmaf(hf[r], q.z, acc[s * 4 + 2]);
          acc[s * 4 + 3] = fmaf(hf[r], q.w, acc[s * 4 + 3]);
        }
      }
    }
    const float fire = fireL[pw];
    const int base = ((b * H_ + h) * W_ + w0 + pw) * C_ + c0;
#pragma unroll
    for (int s = 0; s < 3; ++s) {
      float4 xc = *(const float4*)&xin[base + s * 4];
      float outv[4] = { xc.x, xc.y, xc.z, xc.w };
#pragma unroll
      for (int j = 0; j < 4; ++j) {
        float d = acc[s * 4 + j] * fire;
        if (c0 + s * 4 + j < 3) d = 0.f;   // frozen image channels
        outv[j] += d;
      }
      *(float4*)&xout[base + s * 4] = make_float4(outv[0], outv[1], outv[2], outv[3]);
    }
  }
}

extern "C" void kernel_launch(void* const* d_in, const int* in_sizes, int n_in,
                              void* d_out, int out_size, void* d_ws, size_t ws_size,
                              hipStream_t stream) {
  const float* xin = (const float*)d_in[0];
  const float* f0  = (const float*)d_in[1];
  const float* f1  = (const float*)d_in[2];
  const float* w1  = (const float*)d_in[3];
  const float* b1  = (const float*)d_in[4];
  const float* w2  = (const float*)d_in[5];
  float* xout = (float*)d_out;
  (void)in_sizes; (void)n_in; (void)out_size; (void)ws_size;  // steps fixed = 4

  const size_t N = (size_t)NTOT;

  // Per-step fire keys (host-side integer math):
  // folded = tf(key(42)=(0,42), (0,i)); then split -> k1 per FIRE_MODE.
  unsigned ka[4], kb[4];
  for (int i = 0; i < 4; ++i) {
    U2 fold = threefry2x32(0u, 42u, 0u, (unsigned)i);
#if FIRE_MODE == 3
    // legacy split: counts [0,1,2,3] -> pairs (0,2),(1,3); k1 = (r0.x, r1.x)
    U2 r0 = threefry2x32(fold.x, fold.y, 0u, 2u);
    U2 r1 = threefry2x32(fold.x, fold.y, 1u, 3u);
    ka[i] = r0.x; kb[i] = r1.x;
#else
    // partitionable split: k1 = tf(folded, (0,0))
    U2 k1 = threefry2x32(fold.x, fold.y, 0u, 0u);
    ka[i] = k1.x; kb[i] = k1.y;
#endif
  }

  // ws layout: [w1p 36864 f][w2cm 12288 f][bufA N f]  (~101 MB)
  float* w1p  = (float*)d_ws;
  float* w2cm = w1p + HID_ * F_;
  float* bufA = w2cm + C_ * HID_;

  const dim3 gs(B_ * H_ * (W_ / PW_));   // 8192
  const dim3 bs(256);

  nca_pack<<<144, 256, 0, stream>>>(w1, w2, w1p, w2cm);
  // in -> A -> out -> A -> out
  nca_step<<<gs, bs, 0, stream>>>(xin,  bufA, f0, f1, w1p, b1, w2cm, ka[0], kb[0]);
  nca_step<<<gs, bs, 0, stream>>>(bufA, xout, f0, f1, w1p, b1, w2cm, ka[1], kb[1]);
  nca_step<<<gs, bs, 0, stream>>>(xout, bufA, f0, f1, w1p, b1, w2cm, ka[2], kb[2]);
  nca_step<<<gs, bs, 0, stream>>>(bufA, xout, f0, f1, w1p, b1, w2cm, ka[3], kb[3]);
}

// Round 3
// 850.820 us; speedup vs baseline: 5.5028x; 5.5028x over previous
//
#include <hip/hip_runtime.h>
#include <stdint.h>
#include <stddef.h>

// BasicNCAModel: 4 NCA steps on x[8,256,256,48], fp32 I/O.
// Per step: p = [x, dwconv(x,f0), dwconv(x,f1)] (reflect), h = leaky(p@w1^T+b1),
// d = h@w2^T, d *= fire(threefry) ; d[:, :3]=0 ; x += d.
// This version: both GEMMs on bf16 MFMA 16x16x32; conv fp32 VALU; x carried fp32.

#define B_   8
#define H_   256
#define W_   256
#define C_   48
#define F_   144          // 3*C
#define FP_  160          // F padded to 5*32 for MFMA K
#define HID_ 256
#define PW_  64           // pixels per block
#define NTOT (B_*H_*W_*C_)

typedef __attribute__((ext_vector_type(8))) short short8;   // 8 bf16 (4 VGPRs)
typedef __attribute__((ext_vector_type(4))) float f32x4;

struct U2 { unsigned x, y; };

__host__ __device__ __forceinline__ unsigned rotl32(unsigned v, int r) {
  return (v << r) | (v >> (32 - r));
}

// JAX Threefry-2x32, 20 rounds.
__host__ __device__ __forceinline__ U2 threefry2x32(unsigned k0, unsigned k1,
                                                    unsigned x0, unsigned x1) {
  const unsigned k2 = k0 ^ k1 ^ 0x1BD11BDAu;
  x0 += k0; x1 += k1;
#define TF_R(r) { x0 += x1; x1 = rotl32(x1, r); x1 ^= x0; }
  TF_R(13) TF_R(15) TF_R(26) TF_R(6)
  x0 += k1; x1 += k2 + 1u;
  TF_R(17) TF_R(29) TF_R(16) TF_R(24)
  x0 += k2; x1 += k0 + 2u;
  TF_R(13) TF_R(15) TF_R(26) TF_R(6)
  x0 += k0; x1 += k1 + 3u;
  TF_R(17) TF_R(29) TF_R(16) TF_R(24)
  x0 += k1; x1 += k2 + 4u;
  TF_R(13) TF_R(15) TF_R(26) TF_R(6)
  x0 += k2; x1 += k0 + 5u;
#undef TF_R
  U2 r; r.x = x0; r.y = x1; return r;
}

__device__ __forceinline__ unsigned short f2bf(float f) {  // RNE
  unsigned u = __float_as_uint(f);
  unsigned r = u + 0x7FFFu + ((u >> 16) & 1u);
  return (unsigned short)(r >> 16);
}
__device__ __forceinline__ unsigned packbf2(float lo, float hi) {
  return (unsigned)f2bf(lo) | ((unsigned)f2bf(hi) << 16);
}

// ---- weight pack: B-operand fragment layouts (bf16) ----
// w1B[((nt*5+ks)*64+lane)*8+j] = w1[o=nt*16+(lane&15)][f=ks*32+(lane>>4)*8+j], 0 if f>=144
// w2B[((nt*8+ks)*64+lane)*8+j] = w2[c=nt*16+(lane&15)][o=ks*32+(lane>>4)*8+j]
#define W1B_N 40960   // 16*5*64*8
#define W2B_N 12288   // 3*8*64*8
__global__ void nca_pack(const float* __restrict__ w1,
                         const float* __restrict__ w2,
                         unsigned short* __restrict__ w1B,
                         unsigned short* __restrict__ w2B) {
  int i = blockIdx.x * 256 + threadIdx.x;
  if (i < W1B_N) {
    int nt = i / 2560, r = i - nt * 2560;
    int ks = r >> 9, r2 = r & 511;
    int lane = r2 >> 3, j = r2 & 7;
    int o = nt * 16 + (lane & 15);
    int f = ks * 32 + (lane >> 4) * 8 + j;
    float v = (f < F_) ? w1[o * F_ + f] : 0.0f;
    w1B[i] = f2bf(v);
  }
  if (i < W2B_N) {
    int nt = i >> 12, r = i & 4095;
    int ks = r >> 9, r2 = r & 511;
    int lane = r2 >> 3, j = r2 & 7;
    int c = nt * 16 + (lane & 15);
    int o = ks * 32 + (lane >> 4) * 8 + j;
    w2B[i] = f2bf(w2[c * HID_ + o]);
  }
}

__global__ __launch_bounds__(256, 2)
void nca_step(const float* __restrict__ xin, float* __restrict__ xout,
              const float* __restrict__ f0,
              const float* __restrict__ f1,
              const unsigned short* __restrict__ w1B,
              const float* __restrict__ b1,
              const unsigned short* __restrict__ w2B,
              unsigned ka, unsigned kb) {
  // pA: GEMM1 A-operand fragments  [mt(4)][ks(5)][lane(64)][j(8)] bf16
  // hA: GEMM2 A-operand fragments  [mt(4)][ks(8)][lane(64)][j(8)] bf16
  __shared__ __align__(16) short pA[4 * 5 * 64 * 8];   // 20480 B
  __shared__ __align__(16) short hA[4 * 8 * 64 * 8];   // 32768 B
  __shared__ float fireL[PW_];

  const int t = threadIdx.x;
  const int bid = blockIdx.x;
  const int wseg = bid & 3;
  const int h = (bid >> 2) & 255;
  const int b = bid >> 10;
  const int w0 = wseg * PW_;
  const int gbase = ((b * H_ + h) * W_ + w0) * C_;

  if (t < PW_) {
    unsigned j = (unsigned)((b * H_ + h) * W_ + w0 + t);
    U2 r = threefry2x32(ka, kb, 0u, j);
    unsigned bits = r.x ^ r.y;                       // partitionable xor
    fireL[t] = ((bits >> 9) > 4194304u) ? 1.0f : 0.0f;
  }
  // zero-pad region of pA: ks=4, lane>=32 (k in [144,160))
  if (t < 128) {
    int mt = t >> 5, lane = 32 + (t & 31);
    *(short8*)&pA[(((mt * 5 + 4) << 6) | lane) << 3] = short8{0,0,0,0,0,0,0,0};
  }

  // ---- Phase A: conv -> pA in A-fragment layout (channel pairs) ----
  {
    const int hr0 = (h == 0) ? 1 : h - 1;
    const int hr2 = (h == 255) ? 254 : h + 1;
    const int hrow[3] = { (b * H_ + hr0) * W_, (b * H_ + h) * W_, (b * H_ + hr2) * W_ };
#pragma unroll
    for (int it = 0; it < 6; ++it) {
      int item = t + it * 256;               // 1536 = 64 px * 24 ch-pairs
      int px = item / 24, cp = item - px * 24;
      int c = cp * 2;
      int wg = w0 + px;
      int wr[3] = { (wg == 0) ? 1 : wg - 1, wg, (wg == 255) ? 254 : wg + 1 };
      float a0x = 0.f, a0y = 0.f, a1x = 0.f, a1y = 0.f, cx = 0.f, cy = 0.f;
#pragma unroll
      for (int iy = 0; iy < 3; ++iy) {
#pragma unroll
        for (int ix = 0; ix < 3; ++ix) {
          const float2 v = *(const float2*)&xin[(hrow[iy] + wr[ix]) * C_ + c];
          const float g0a = f0[c * 9 + iy * 3 + ix];
          const float g0b = f0[(c + 1) * 9 + iy * 3 + ix];
          const float g1a = f1[c * 9 + iy * 3 + ix];
          const float g1b = f1[(c + 1) * 9 + iy * 3 + ix];
          a0x = fmaf(v.x, g0a, a0x); a0y = fmaf(v.y, g0b, a0y);
          a1x = fmaf(v.x, g1a, a1x); a1y = fmaf(v.y, g1b, a1y);
          if (iy == 1 && ix == 1) { cx = v.x; cy = v.y; }
        }
      }
      const int mt = px >> 4, pxl = px & 15;
      unsigned* pA32 = (unsigned*)pA;
#pragma unroll
      for (int seg = 0; seg < 3; ++seg) {
        int k = seg * 48 + c;
        int ks = k >> 5, q = (k & 31) >> 3, jw = (k & 7) >> 1;
        int lane2 = pxl + (q << 4);
        int dw = (((mt * 5 + ks) << 6) | lane2) * 4 + jw;
        float lo = (seg == 0) ? cx : (seg == 1) ? a0x : a1x;
        float hi = (seg == 0) ? cy : (seg == 1) ? a0y : a1y;
        pA32[dw] = packbf2(lo, hi);
      }
    }
  }
  __syncthreads();

  // ---- GEMM1: h = leaky(p @ w1^T + b1), MFMA 16x16x32 ----
  const int wv = t >> 6, lane = t & 63;
  const int c16 = lane & 15, quad = lane >> 4;
  {
    short8 a[4][5];
#pragma unroll
    for (int mt = 0; mt < 4; ++mt)
#pragma unroll
      for (int ks = 0; ks < 5; ++ks)
        a[mt][ks] = *(const short8*)&pA[(((mt * 5 + ks) << 6) | lane) << 3];

    f32x4 acc[4][4];
#pragma unroll
    for (int mt = 0; mt < 4; ++mt)
#pragma unroll
      for (int nt = 0; nt < 4; ++nt) acc[mt][nt] = f32x4{0.f, 0.f, 0.f, 0.f};

#pragma unroll
    for (int nt = 0; nt < 4; ++nt) {
      const int ntg = wv * 4 + nt;
#pragma unroll
      for (int ks = 0; ks < 5; ++ks) {
        const short8 bfr = *(const short8*)&w1B[(((ntg * 5 + ks) << 6) | lane) << 3];
#pragma unroll
        for (int mt = 0; mt < 4; ++mt)
          acc[mt][nt] = __builtin_amdgcn_mfma_f32_16x16x32_bf16(a[mt][ks], bfr, acc[mt][nt], 0, 0, 0);
      }
    }

    // epilogue: bias + leaky + scatter into hA (GEMM2 A-fragment layout)
#pragma unroll
    for (int nt = 0; nt < 4; ++nt) {
      const int o = (wv * 4 + nt) * 16 + c16;
      const float bias = b1[o];
      const int ks2 = o >> 5, q2 = (o & 31) >> 3, j2 = o & 7;
#pragma unroll
      for (int mt = 0; mt < 4; ++mt) {
#pragma unroll
        for (int reg = 0; reg < 4; ++reg) {
          float z = acc[mt][nt][reg] + bias;
          z = (z >= 0.f) ? z : 0.01f * z;
          const int pxl = quad * 4 + reg;
          const int lane2 = pxl + (q2 << 4);
          hA[((((mt * 8 + ks2) << 6) | lane2) << 3) + j2] = (short)f2bf(z);
        }
      }
    }
  }
  __syncthreads();

  // ---- GEMM2: d = h @ w2^T ; mask ; residual store ----
  {
    short8 a2[8];
#pragma unroll
    for (int ks = 0; ks < 8; ++ks)
      a2[ks] = *(const short8*)&hA[(((wv * 8 + ks) << 6) | lane) << 3];

    f32x4 acc2[3];
#pragma unroll
    for (int nt = 0; nt < 3; ++nt) acc2[nt] = f32x4{0.f, 0.f, 0.f, 0.f};

#pragma unroll
    for (int nt = 0; nt < 3; ++nt) {
#pragma unroll
      for (int ks = 0; ks < 8; ++ks) {
        const short8 bfr = *(const short8*)&w2B[(((nt * 8 + ks) << 6) | lane) << 3];
        acc2[nt] = __builtin_amdgcn_mfma_f32_16x16x32_bf16(a2[ks], bfr, acc2[nt], 0, 0, 0);
      }
    }

#pragma unroll
    for (int nt = 0; nt < 3; ++nt) {
      const int c = nt * 16 + c16;
#pragma unroll
      for (int reg = 0; reg < 4; ++reg) {
        const int pxl = wv * 16 + quad * 4 + reg;
        float d = acc2[nt][reg] * fireL[pxl];
        if (c < 3) d = 0.f;                       // frozen image channels
        const int idx = gbase + pxl * C_ + c;
        xout[idx] = xin[idx] + d;
      }
    }
  }
}

extern "C" void kernel_launch(void* const* d_in, const int* in_sizes, int n_in,
                              void* d_out, int out_size, void* d_ws, size_t ws_size,
                              hipStream_t stream) {
  const float* xin = (const float*)d_in[0];
  const float* f0  = (const float*)d_in[1];
  const float* f1  = (const float*)d_in[2];
  const float* w1  = (const float*)d_in[3];
  const float* b1  = (const float*)d_in[4];
  const float* w2  = (const float*)d_in[5];
  float* xout = (float*)d_out;
  (void)in_sizes; (void)n_in; (void)out_size; (void)ws_size;  // steps fixed = 4

  // Per-step fire keys: folded = tf(key(42),(0,i)); k1 = tf(folded,(0,0)).
  unsigned ka[4], kb[4];
  for (int i = 0; i < 4; ++i) {
    U2 fold = threefry2x32(0u, 42u, 0u, (unsigned)i);
    U2 k1 = threefry2x32(fold.x, fold.y, 0u, 0u);
    ka[i] = k1.x; kb[i] = k1.y;
  }

  // ws layout: [w1B bf16 40960][w2B bf16 12288][pad to 16B][bufA fp32 N]
  unsigned short* w1B = (unsigned short*)d_ws;
  unsigned short* w2B = w1B + W1B_N;
  float* bufA = (float*)(((char*)d_ws) + ((W1B_N + W2B_N) * 2 + 15) / 16 * 16);

  const dim3 gs(B_ * H_ * (W_ / PW_));   // 8192
  const dim3 bs(256);

  nca_pack<<<(W1B_N + 255) / 256, 256, 0, stream>>>(w1, w2, w1B, w2B);
  // in -> A -> out -> A -> out
  nca_step<<<gs, bs, 0, stream>>>(xin,  bufA, f0, f1, w1B, b1, w2B, ka[0], kb[0]);
  nca_step<<<gs, bs, 0, stream>>>(bufA, xout, f0, f1, w1B, b1, w2B, ka[1], kb[1]);
  nca_step<<<gs, bs, 0, stream>>>(xout, bufA, f0, f1, w1B, b1, w2B, ka[2], kb[2]);
  nca_step<<<gs, bs, 0, stream>>>(bufA, xout, f0, f1, w1B, b1, w2B, ka[3], kb[3]);
}

// Round 4
// 818.502 us; speedup vs baseline: 5.7201x; 1.0395x over previous
//
#include <hip/hip_runtime.h>
#include <stdint.h>
#include <stddef.h>

// BasicNCAModel: 4 NCA steps on x[8,256,256,48], fp32 I/O.
// Per step: p = [x, dwconv(x,f0), dwconv(x,f1)] (reflect), h = leaky(p@w1^T+b1),
// d = h@w2^T, d *= fire(threefry) ; d[:, :3]=0 ; x += d.
// R4: x-tile staged bf16 in LDS (conv reads LDS, packed filters in regs),
//     pA/hA/xT share one 39.5 KB LDS region -> 4 blocks/CU, ks-outer GEMM1.

#define B_   8
#define H_   256
#define W_   256
#define C_   48
#define F_   144
#define HID_ 256
#define PW_  64
#define NTOT (B_*H_*W_*C_)

typedef __attribute__((ext_vector_type(8))) short short8;   // 8 bf16
typedef __attribute__((ext_vector_type(4))) float f32x4;

struct U2 { unsigned x, y; };

__host__ __device__ __forceinline__ unsigned rotl32(unsigned v, int r) {
  return (v << r) | (v >> (32 - r));
}

// JAX Threefry-2x32, 20 rounds.
__host__ __device__ __forceinline__ U2 threefry2x32(unsigned k0, unsigned k1,
                                                    unsigned x0, unsigned x1) {
  const unsigned k2 = k0 ^ k1 ^ 0x1BD11BDAu;
  x0 += k0; x1 += k1;
#define TF_R(r) { x0 += x1; x1 = rotl32(x1, r); x1 ^= x0; }
  TF_R(13) TF_R(15) TF_R(26) TF_R(6)
  x0 += k1; x1 += k2 + 1u;
  TF_R(17) TF_R(29) TF_R(16) TF_R(24)
  x0 += k2; x1 += k0 + 2u;
  TF_R(13) TF_R(15) TF_R(26) TF_R(6)
  x0 += k0; x1 += k1 + 3u;
  TF_R(17) TF_R(29) TF_R(16) TF_R(24)
  x0 += k1; x1 += k2 + 4u;
  TF_R(13) TF_R(15) TF_R(26) TF_R(6)
  x0 += k2; x1 += k0 + 5u;
#undef TF_R
  U2 r; r.x = x0; r.y = x1; return r;
}

__device__ __forceinline__ unsigned short f2bf(float f) {  // RNE
  unsigned u = __float_as_uint(f);
  unsigned r = u + 0x7FFFu + ((u >> 16) & 1u);
  return (unsigned short)(r >> 16);
}
__device__ __forceinline__ unsigned packbf2(float lo, float hi) {
  return (unsigned)f2bf(lo) | ((unsigned)f2bf(hi) << 16);
}

// ---- pack: B-fragment weights (bf16) + packed conv filters ----
// w1B[((nt*5+ks)*64+lane)*8+j] = w1[o=nt*16+(lane&15)][f=ks*32+(lane>>4)*8+j] (0 pad f>=144)
// w2B[((nt*8+ks)*64+lane)*8+j] = w2[c=nt*16+(lane&15)][o=ks*32+(lane>>4)*8+j]
// ffp[cp*9+tap] = {f0[2cp][tap], f0[2cp+1][tap], f1[2cp][tap], f1[2cp+1][tap]}
#define W1B_N 40960
#define W2B_N 12288
__global__ void nca_pack(const float* __restrict__ w1,
                         const float* __restrict__ w2,
                         const float* __restrict__ f0,
                         const float* __restrict__ f1,
                         unsigned short* __restrict__ w1B,
                         unsigned short* __restrict__ w2B,
                         float4* __restrict__ ffp) {
  int i = blockIdx.x * 256 + threadIdx.x;
  if (i < W1B_N) {
    int nt = i / 2560, r = i - nt * 2560;
    int ks = r >> 9, r2 = r & 511;
    int lane = r2 >> 3, j = r2 & 7;
    int o = nt * 16 + (lane & 15);
    int f = ks * 32 + (lane >> 4) * 8 + j;
    w1B[i] = f2bf((f < F_) ? w1[o * F_ + f] : 0.0f);
  }
  if (i < W2B_N) {
    int nt = i >> 12, r = i & 4095;
    int ks = r >> 9, r2 = r & 511;
    int lane = r2 >> 3, j = r2 & 7;
    int c = nt * 16 + (lane & 15);
    int o = ks * 32 + (lane >> 4) * 8 + j;
    w2B[i] = f2bf(w2[c * HID_ + o]);
  }
  if (i < 216) {
    int cp = i / 9, tap = i - cp * 9;
    float4 v;
    v.x = f0[(2 * cp) * 9 + tap];     v.y = f0[(2 * cp + 1) * 9 + tap];
    v.z = f1[(2 * cp) * 9 + tap];     v.w = f1[(2 * cp + 1) * 9 + tap];
    ffp[i] = v;
  }
}

__global__ __launch_bounds__(256, 4)
void nca_step(const float* __restrict__ xin, float* __restrict__ xout,
              const float4* __restrict__ ffp,
              const unsigned short* __restrict__ w1B,
              const float* __restrict__ b1,
              const unsigned short* __restrict__ w2B,
              unsigned ka, unsigned kb) {
  // Aliased LDS region (39488 B):
  //   xT [0,19008)      : x tile [3 rows][66 px][48 ch] bf16
  //   pA [19008,39488)  : GEMM1 A-frags [4mt*5ks][64 lane][8 j] bf16
  //   hA [0,32768)      : GEMM2 A-frags [4mt*8ks][64 lane][8 j] bf16 (after xT/pA dead)
  __shared__ __align__(16) char smem[39488];
  __shared__ float fireL[PW_];
  short* xT = (short*)smem;
  short* pA = (short*)(smem + 19008);
  short* hA = (short*)smem;

  const int t = threadIdx.x;
  const int bid = blockIdx.x;
  const int wseg = bid & 3;
  const int h = (bid >> 2) & 255;
  const int b = bid >> 10;
  const int w0 = wseg * PW_;
  const int gbase = ((b * H_ + h) * W_ + w0) * C_;

  // ---- Stage: fire RNG, pA K-pad zeros, x tile (bf16, reflect resolved) ----
  if (t < PW_) {
    unsigned j = (unsigned)((b * H_ + h) * W_ + w0 + t);
    U2 r = threefry2x32(ka, kb, 0u, j);
    unsigned bits = r.x ^ r.y;
    fireL[t] = ((bits >> 9) > 4194304u) ? 1.0f : 0.0f;
  } else if (t < 192) {
    int idx = t - 64;                       // zero pA k in [144,160)
    int mt = idx >> 5, lane = 32 + (idx & 31);
    short8 z = {};
    *(short8*)&pA[(((mt * 5 + 4) << 6) | lane) << 3] = z;
  }
  {
    const int hr[3] = { (h == 0) ? 1 : h - 1, h, (h == 255) ? 254 : h + 1 };
#pragma unroll
    for (int g = 0; g < 10; ++g) {
      int i = t + g * 256;                  // 2376 = 3 rows * 66 px * 12 c4
      if (i < 2376) {
        int row = i / 792, rem = i - row * 792;
        int px = rem / 12, c4 = rem - px * 12;
        int w = w0 - 1 + px;
        int wg = (w < 0) ? 1 : (w > 255) ? 254 : w;
        const float4 v = *(const float4*)&xin[((b * H_ + hr[row]) * W_ + wg) * C_ + c4 * 4];
        uint2 d; d.x = packbf2(v.x, v.y); d.y = packbf2(v.z, v.w);
        *(uint2*)&xT[(row * 66 + px) * 48 + c4 * 4] = d;
      }
    }
  }
  __syncthreads();

  // ---- Conv: 24 ch-pairs x 8 threads x 8 px, filters in regs, x from LDS ----
  if (t < 192) {
    const int cp = t >> 3, sub = t & 7;
    const int c = cp * 2;
    float4 ff[9];
#pragma unroll
    for (int tap = 0; tap < 9; ++tap) ff[tap] = ffp[cp * 9 + tap];
    unsigned* pA32 = (unsigned*)pA;
#pragma unroll
    for (int i = 0; i < 8; ++i) {
      const int p = sub + 8 * i;            // pixel 0..63
      float a0x = 0.f, a0y = 0.f, a1x = 0.f, a1y = 0.f, cx = 0.f, cy = 0.f;
#pragma unroll
      for (int dy = 0; dy < 3; ++dy) {
#pragma unroll
        for (int dx = 0; dx < 3; ++dx) {
          unsigned d = *(const unsigned*)&xT[(dy * 66 + p + dx) * 48 + c];
          float lo = __uint_as_float(d << 16);
          float hi = __uint_as_float(d & 0xFFFF0000u);
          const float4 f = ff[dy * 3 + dx];
          a0x = fmaf(lo, f.x, a0x); a0y = fmaf(hi, f.y, a0y);
          a1x = fmaf(lo, f.z, a1x); a1y = fmaf(hi, f.w, a1y);
          if (dy == 1 && dx == 1) { cx = lo; cy = hi; }
        }
      }
      const int mt = p >> 4, pxl = p & 15;
#pragma unroll
      for (int seg = 0; seg < 3; ++seg) {
        int k = seg * 48 + c;
        int ks = k >> 5, q = (k & 31) >> 3, jw = (k & 7) >> 1;
        int lane2 = pxl + (q << 4);
        float lo = (seg == 0) ? cx : (seg == 1) ? a0x : a1x;
        float hi = (seg == 0) ? cy : (seg == 1) ? a0y : a1y;
        pA32[(((mt * 5 + ks) << 6) | lane2) * 4 + jw] = packbf2(lo, hi);
      }
    }
  }
  __syncthreads();

  // ---- GEMM1: h = leaky(p @ w1^T + b1), 16x16x32, ks-outer ----
  const int wv = t >> 6, lane = t & 63;
  const int c16 = lane & 15, quad = lane >> 4;
  f32x4 acc[4][4];
#pragma unroll
  for (int mt = 0; mt < 4; ++mt)
#pragma unroll
    for (int nt = 0; nt < 4; ++nt) acc[mt][nt] = f32x4{0.f, 0.f, 0.f, 0.f};

#pragma unroll
  for (int ks = 0; ks < 5; ++ks) {
    short8 a[4];
#pragma unroll
    for (int mt = 0; mt < 4; ++mt)
      a[mt] = *(const short8*)&pA[(((mt * 5 + ks) << 6) | lane) << 3];
#pragma unroll
    for (int nt = 0; nt < 4; ++nt) {
      const int ntg = wv * 4 + nt;
      const short8 bf = *(const short8*)&w1B[(((ntg * 5 + ks) << 6) | lane) << 3];
#pragma unroll
      for (int mt = 0; mt < 4; ++mt)
        acc[mt][nt] = __builtin_amdgcn_mfma_f32_16x16x32_bf16(a[mt], bf, acc[mt][nt], 0, 0, 0);
    }
  }
  __syncthreads();   // all pA reads complete before hA (aliased) is written

  // epilogue: bias + leaky -> hA (GEMM2 A-frag layout)
#pragma unroll
  for (int nt = 0; nt < 4; ++nt) {
    const int o = (wv * 4 + nt) * 16 + c16;
    const float bias = b1[o];
    const int ks2 = o >> 5, q2 = (o & 31) >> 3, j2 = o & 7;
#pragma unroll
    for (int mt = 0; mt < 4; ++mt) {
#pragma unroll
      for (int reg = 0; reg < 4; ++reg) {
        float z = acc[mt][nt][reg] + bias;
        z = (z >= 0.f) ? z : 0.01f * z;
        const int lane2 = (quad * 4 + reg) + (q2 << 4);
        hA[((((mt * 8 + ks2) << 6) | lane2) << 3) + j2] = (short)f2bf(z);
      }
    }
  }
  __syncthreads();

  // ---- GEMM2: d = h @ w2^T ; fire & channel mask ; residual store ----
  {
    f32x4 acc2[3];
#pragma unroll
    for (int nt = 0; nt < 3; ++nt) acc2[nt] = f32x4{0.f, 0.f, 0.f, 0.f};
#pragma unroll
    for (int ks = 0; ks < 8; ++ks) {
      const short8 a2 = *(const short8*)&hA[(((wv * 8 + ks) << 6) | lane) << 3];
#pragma unroll
      for (int nt = 0; nt < 3; ++nt) {
        const short8 bf = *(const short8*)&w2B[(((nt * 8 + ks) << 6) | lane) << 3];
        acc2[nt] = __builtin_amdgcn_mfma_f32_16x16x32_bf16(a2, bf, acc2[nt], 0, 0, 0);
      }
    }
#pragma unroll
    for (int nt = 0; nt < 3; ++nt) {
      const int c = nt * 16 + c16;
#pragma unroll
      for (int reg = 0; reg < 4; ++reg) {
        const int pxl = wv * 16 + quad * 4 + reg;
        float d = acc2[nt][reg] * fireL[pxl];
        if (c < 3) d = 0.f;
        const int idx = gbase + pxl * C_ + c;
        xout[idx] = xin[idx] + d;
      }
    }
  }
}

extern "C" void kernel_launch(void* const* d_in, const int* in_sizes, int n_in,
                              void* d_out, int out_size, void* d_ws, size_t ws_size,
                              hipStream_t stream) {
  const float* xin = (const float*)d_in[0];
  const float* f0  = (const float*)d_in[1];
  const float* f1  = (const float*)d_in[2];
  const float* w1  = (const float*)d_in[3];
  const float* b1  = (const float*)d_in[4];
  const float* w2  = (const float*)d_in[5];
  float* xout = (float*)d_out;
  (void)in_sizes; (void)n_in; (void)out_size; (void)ws_size;

  // Per-step fire keys: folded = tf(key(42),(0,i)); k1 = tf(folded,(0,0)); xor-bits.
  unsigned ka[4], kb[4];
  for (int i = 0; i < 4; ++i) {
    U2 fold = threefry2x32(0u, 42u, 0u, (unsigned)i);
    U2 k1 = threefry2x32(fold.x, fold.y, 0u, 0u);
    ka[i] = k1.x; kb[i] = k1.y;
  }

  // ws: [w1B 81920B][w2B 24576B][ffp 3456B][bufA fp32 N]
  unsigned short* w1B = (unsigned short*)d_ws;
  unsigned short* w2B = w1B + W1B_N;
  float4* ffp = (float4*)((char*)d_ws + (W1B_N + W2B_N) * 2);
  float* bufA = (float*)((char*)d_ws + (W1B_N + W2B_N) * 2 + 216 * 16);

  const dim3 gs(B_ * H_ * (W_ / PW_));   // 8192
  const dim3 bs(256);

  nca_pack<<<(W1B_N + 255) / 256, 256, 0, stream>>>(w1, w2, f0, f1, w1B, w2B, ffp);
  nca_step<<<gs, bs, 0, stream>>>(xin,  bufA, ffp, w1B, b1, w2B, ka[0], kb[0]);
  nca_step<<<gs, bs, 0, stream>>>(bufA, xout, ffp, w1B, b1, w2B, ka[1], kb[1]);
  nca_step<<<gs, bs, 0, stream>>>(xout, bufA, ffp, w1B, b1, w2B, ka[2], kb[2]);
  nca_step<<<gs, bs, 0, stream>>>(bufA, xout, ffp, w1B, b1, w2B, ka[3], kb[3]);
}